// Round 4
// baseline (201.572 us; speedup 1.0000x reference)
//
#include <hip/hip_runtime.h>
#include <hip/hip_bf16.h>

#define B_ 2
#define T_ 2048
#define H_ 1024
#define NH_ 16
#define D_ 64
#define BT_ (B_*T_)
#define SCALE_ 0.125f
#define LOG2E_ 1.4426950408889634f

typedef _Float16 f16x8 __attribute__((ext_vector_type(8)));
typedef float f32x4 __attribute__((ext_vector_type(4)));

#define MFMA(a,b,c) __builtin_amdgcn_mfma_f32_16x16x32_f16((a),(b),(c),0,0,0)
#define EXP2(x) __builtin_amdgcn_exp2f(x)

typedef const __attribute__((address_space(1))) void GV;
typedef __attribute__((address_space(3))) void LV;

// Fragment-tiled layout: matrix [R x C] consumed by MFMA with k-dim = C.
// 16-row tiles, 32-wide k-chunks; chunk block = [quad(k/8)][row%16][k%8] = 512 f16 = 1KB.
__device__ __forceinline__ size_t toff(int r, int c, int C) {
    return (size_t)((r >> 4) * (C >> 5) + (c >> 5)) * 512 + (size_t)(((c & 31) >> 3) * 128 + (r & 15) * 8 + (c & 7));
}
__device__ __forceinline__ f16x8 frag_ld(const _Float16* base, int rt, int kc, int Cc, int l15, int quad) {
    return *(const f16x8*)(base + (size_t)(rt * Cc + kc) * 512 + quad * 128 + l15 * 8);
}
// pass2 strip-base: number of 128-wide s-tiles in strips < p. f(2m)=m*m+m, f(2m+1)=(m+1)^2
__device__ __forceinline__ int fbase(int p) {
    int m = p >> 1;
    return (p & 1) ? (m + 1) * (m + 1) : m * m + m;
}

// ---------- prep: all stores are contiguous f16x8 bursts; transposes are load-side ----------
// blocks: [0,256) x-cast | [256,384) wqk | [384,388) wvt | [388,392) wot | [392,1384) mw-zero
__global__ __launch_bounds__(256) void k_prep(const float* __restrict__ x,
                                              const float* __restrict__ Wq, const float* __restrict__ Wk,
                                              const float* __restrict__ Wv, const float* __restrict__ Wo,
                                              _Float16* __restrict__ xb, _Float16* __restrict__ wqk,
                                              _Float16* __restrict__ wvt, _Float16* __restrict__ wot,
                                              float* __restrict__ mw) {
    int blk = blockIdx.x, tid = threadIdx.x;
    if (blk < 256) {                               // cast x: 16 t-rows/block, output tile contiguous 32KB
        const float* xs = x + ((size_t)blk << 14);
        _Float16* dstb = xb + ((size_t)blk << 14);
#pragma unroll
        for (int it = 0; it < 8; it++) {
            int E = it * 2048 + tid * 8;
            int rr = (E >> 3) & 15;
            int h = (E >> 9) * 32 + ((E >> 7) & 3) * 8;
            const float* p = xs + (size_t)rr * 1024 + h;
            float4 f0 = *(const float4*)p;
            float4 f1 = *(const float4*)(p + 4);
            f16x8 o;
            o[0]=(_Float16)f0.x; o[1]=(_Float16)f0.y; o[2]=(_Float16)f0.z; o[3]=(_Float16)f0.w;
            o[4]=(_Float16)f1.x; o[5]=(_Float16)f1.y; o[6]=(_Float16)f1.z; o[7]=(_Float16)f1.w;
            *(f16x8*)(dstb + E) = o;
        }
    } else if (blk < 384) {                        // wqk: one 16-row c-tile per block, stride-64 gathers
        int ct = blk - 256;                        // 0..63 q-tiles, 64..127 k-tiles
        const float* W = (ct < 64) ? Wq : Wk;
        int head = (ct >> 2) & 15;
        int dbase = (ct & 3) * 16;
        _Float16* dstb = wqk + ((size_t)ct << 14);
#pragma unroll
        for (int it = 0; it < 8; it++) {
            int E = it * 2048 + tid * 8;
            int rr = (E >> 3) & 15;
            int h = (E >> 9) * 32 + ((E >> 7) & 3) * 8;
            const float* src = W + (size_t)head * 65536 + (size_t)h * 64 + dbase + rr;
            f16x8 o;
#pragma unroll
            for (int e = 0; e < 8; e++) o[e] = (_Float16)src[(size_t)e * 64];
            *(f16x8*)(dstb + E) = o;
        }
    } else if (blk < 388) {                        // wvt: rows=d (4 tiles), cols=h, stride-64 gathers
        int rt = blk - 384;
        _Float16* dstb = wvt + ((size_t)rt << 14);
#pragma unroll
        for (int it = 0; it < 8; it++) {
            int E = it * 2048 + tid * 8;
            int rr = (E >> 3) & 15;
            int h = (E >> 9) * 32 + ((E >> 7) & 3) * 8;
            const float* src = Wv + (size_t)h * 64 + rt * 16 + rr;
            f16x8 o;
#pragma unroll
            for (int e = 0; e < 8; e++) o[e] = (_Float16)src[(size_t)e * 64];
            *(f16x8*)(dstb + E) = o;
        }
    } else if (blk < 392) {                        // wot: rows=h (C=64), stride-1024 gathers
        int bl = blk - 388;
#pragma unroll
        for (int it = 0; it < 8; it++) {
            int G = bl * 16384 + it * 2048 + tid * 8;
            int rt = G >> 10;
            int rem = G & 1023;
            int rr = (rem >> 3) & 15;
            int dd = (rem >> 9) * 32 + ((rem >> 7) & 3) * 8;
            const float* src = Wo + (size_t)dd * 1024 + rt * 16 + rr;
            f16x8 o;
#pragma unroll
            for (int e = 0; e < 8; e++) o[e] = (_Float16)src[(size_t)e * 1024];
            *(f16x8*)(wot + G) = o;
        }
    } else {                                       // zero upper-tri tiles (992)
        int iz = blk - 392;
        int b = (iz >= 496) ? 1 : 0;
        int i = iz - b * 496;
        int s64 = (int)((sqrtf(8.f * i + 1.f) + 1.f) * 0.5f);
        if (s64 * (s64 - 1) / 2 > i) s64--;
        if ((s64 + 1) * s64 / 2 <= i) s64++;
        int q64 = i - s64 * (s64 - 1) / 2;         // q64 < s64
        float4 z = {0.f, 0.f, 0.f, 0.f};
#pragma unroll
        for (int it = 0; it < 4; it++) {
            int idx = it * 256 + tid;
            int r = idx >> 4, c4 = idx & 15;
            *(float4*)&mw[(size_t)(b * T_ + q64 * 64 + r) * T_ + s64 * 64 + c4 * 4] = z;
        }
    }
}

// ---------- fused: Q||K GEMM (blocks 0..511, BK=64) + V projection (blocks 512..767) ----------
__global__ __launch_bounds__(256) void k_gemm(const _Float16* __restrict__ xb, const _Float16* __restrict__ wqk,
                                              const float* __restrict__ bq, const float* __restrict__ bk,
                                              const _Float16* __restrict__ wvt, const float* __restrict__ bv,
                                              _Float16* __restrict__ qh, _Float16* __restrict__ kh,
                                              _Float16* __restrict__ vt) {
    __shared__ __align__(16) unsigned char smem[32768];
    _Float16* As = (_Float16*)smem;                // 16 KB
    _Float16* Bs = (_Float16*)(smem + 16384);      // 16 KB
    int tid = threadIdx.x, w = tid >> 6, lane = tid & 63, l15 = lane & 15, quad = lane >> 4;
    if (blockIdx.x >= 512) {                       // ---- vproj path ----
        float (*red)[16][64] = (float(*)[16][64])smem;
        int rt = blockIdx.x - 512;
        f32x4 acc[4];
#pragma unroll
        for (int j = 0; j < 4; j++) acc[j] = (f32x4){0.f, 0.f, 0.f, 0.f};
        for (int q = 0; q < 8; q++) {
            int kc = w * 8 + q;
            f16x8 a = frag_ld(xb, rt, kc, 32, l15, quad);
#pragma unroll
            for (int j = 0; j < 4; j++) {
                f16x8 bb = frag_ld(wvt, j, kc, 32, l15, quad);
                acc[j] = MFMA(a, bb, acc[j]);
            }
        }
#pragma unroll
        for (int j = 0; j < 4; j++)
#pragma unroll
            for (int r = 0; r < 4; r++) red[w][quad * 4 + r][j * 16 + l15] = acc[j][r];
        __syncthreads();
        int r = tid >> 4, dg = tid & 15;
        int b = rt >> 7, tt = (rt & 127) * 16 + r;
        _Float16* vtb = vt + (size_t)b * 131072;
#pragma unroll
        for (int e = 0; e < 4; e++) {
            int d = dg * 4 + e;
            float s = red[0][r][d] + red[1][r][d] + red[2][r][d] + red[3][r][d] + bv[d];
            vtb[toff(d, tt, 2048)] = (_Float16)s;
        }
        return;
    }
    // ---- GEMM path, BK=64 ----
    int bm = blockIdx.x >> 4, bn = blockIdx.x & 15;
    int rowbase = (w >> 1) * 64, colbase = (w & 1) * 64;
    f32x4 acc[4][4];
#pragma unroll
    for (int i = 0; i < 4; i++)
#pragma unroll
        for (int j = 0; j < 4; j++) acc[i][j] = (f32x4){0.f, 0.f, 0.f, 0.f};

    for (int kk = 0; kk < 16; kk++) {
        __syncthreads();
#pragma unroll
        for (int p = 0; p < 4; p++) {
            int c = w * 4 + p;                     // 0..15: rowtile c>>1, k-chunk c&1
            __builtin_amdgcn_global_load_lds((GV*)(xb  + ((size_t)((bm * 8 + (c >> 1)) * 32 + kk * 2 + (c & 1))) * 512 + lane * 8),
                                             (LV*)(As + c * 512 + lane * 8), 16, 0, 0);
            __builtin_amdgcn_global_load_lds((GV*)(wqk + ((size_t)((bn * 8 + (c >> 1)) * 32 + kk * 2 + (c & 1))) * 512 + lane * 8),
                                             (LV*)(Bs + c * 512 + lane * 8), 16, 0, 0);
        }
        __syncthreads();
#pragma unroll
        for (int kc = 0; kc < 2; kc++) {
            f16x8 a[4], bf[4];
#pragma unroll
            for (int i = 0; i < 4; i++) a[i]  = *(const f16x8*)&As[((rowbase >> 4) + i) * 1024 + kc * 512 + quad * 128 + l15 * 8];
#pragma unroll
            for (int j = 0; j < 4; j++) bf[j] = *(const f16x8*)&Bs[((colbase >> 4) + j) * 1024 + kc * 512 + quad * 128 + l15 * 8];
#pragma unroll
            for (int i = 0; i < 4; i++)
#pragma unroll
                for (int j = 0; j < 4; j++) acc[i][j] = MFMA(a[i], bf[j], acc[i][j]);
        }
    }
    __syncthreads();                               // reuse As/Bs for epilogue staging
    int b = (bm * 128) >> 11;
    int t_base = (bm * 128) & 2047;
    int rtbase = (t_base + rowbase) >> 4;
    bool isq = (bn < 8);
    int c2base = isq ? (bn * 128 + colbase) : (bn * 128 + colbase - 1024);
    int n = c2base >> 6;
    _Float16* dst = (isq ? qh : kh) + (size_t)(n * 2 + b) * 131072;
    const float* bias_p = isq ? bq : bk;
    float qs = SCALE_ * LOG2E_;                    // fold softmax scale + log2e into q
    int i2 = lane >> 4, rowrb = lane & 15;
#pragma unroll
    for (int j = 0; j < 4; j++) {
        float bias = bias_p[c2base + j * 16 + l15];
        _Float16* stg = ((j & 1) ? Bs : As) + w * 1024;
#pragma unroll
        for (int i = 0; i < 4; i++)
#pragma unroll
            for (int r = 0; r < 4; r++) {
                float v = acc[i][j][r] + bias;
                if (isq) v *= qs;
                stg[(i * 16 + quad * 4 + r) * 16 + l15] = (_Float16)v;
            }
#pragma unroll
        for (int oct = 0; oct < 2; oct++) {
            f16x8 val = *(const f16x8*)&stg[(i2 * 16 + rowrb) * 16 + oct * 8];
            int dd0 = j * 16 + oct * 8;
            *(f16x8*)(dst + (size_t)((rtbase + i2) * 2 + (dd0 >> 5)) * 512 + ((dd0 & 31) >> 3) * 128 + rowrb * 8) = val;
        }
    }
}

// ---------- pass 1: causal row sum-exp2; 128-row strips, heavy-first, XCD-local (n,b) ----------
__global__ __launch_bounds__(256) void k_pass1(const _Float16* __restrict__ qh, const _Float16* __restrict__ kh,
                                               float* __restrict__ lstat4) {
    int tid = threadIdx.x, w = tid >> 6, lane = tid & 63, l15 = lane & 15, quad = lane >> 4;
    int blk = blockIdx.x;                          // 512 blocks: s8(4) | nb(5)
    int nb = blk & 31;                             // blk&7 ~ XCD -> each XCD serves 4 (n,b) pairs
    int s8 = 15 - (blk >> 5);                      // heavy strips dispatch first
    int n = nb >> 1, b = nb & 1;
    const _Float16* qb = qh + (size_t)(n * 2 + b) * 131072;
    const _Float16* kp = kh + (size_t)(n * 2 + b) * 131072;
    int rt0 = s8 * 8;
    f16x8 aq[8][2];
#pragma unroll
    for (int i = 0; i < 8; i++)
#pragma unroll
        for (int kk = 0; kk < 2; kk++) aq[i][kk] = frag_ld(qb, rt0 + i, kk, 2, l15, quad);
    float l[8][4];
#pragma unroll
    for (int i = 0; i < 8; i++)
#pragma unroll
        for (int r = 0; r < 4; r++) l[i][r] = 0.f;
    int total = 8 * s8 + 8;
    int st_lo = (w * total) >> 2;
    int st_hi = ((w + 1) * total) >> 2;
    for (int st = st_lo; st < st_hi; st++) {
        f16x8 c0 = frag_ld(kp, st, 0, 2, l15, quad);
        f16x8 c1 = frag_ld(kp, st, 1, 2, l15, quad);
#pragma unroll
        for (int i = 0; i < 8; i++) {
            if (st > rt0 + i) continue;            // wave-uniform branch
            f32x4 sc = (f32x4){0.f, 0.f, 0.f, 0.f};
            sc = MFMA(aq[i][0], c0, sc);
            sc = MFMA(aq[i][1], c1, sc);
            if (st == rt0 + i) {
#pragma unroll
                for (int r = 0; r < 4; r++)
                    if (l15 <= quad * 4 + r) l[i][r] += EXP2(sc[r]);
            } else {
#pragma unroll
                for (int r = 0; r < 4; r++) l[i][r] += EXP2(sc[r]);
            }
        }
    }
#pragma unroll
    for (int off = 1; off < 16; off <<= 1)
#pragma unroll
        for (int i = 0; i < 8; i++)
#pragma unroll
            for (int r = 0; r < 4; r++) l[i][r] += __shfl_xor(l[i][r], off, 64);
    if (l15 == 0) {
        int base = (n * 2 + b) * 2048 + s8 * 128;
#pragma unroll
        for (int i = 0; i < 8; i++)
#pragma unroll
            for (int r = 0; r < 4; r++)
                lstat4[(size_t)(base + i * 16 + quad * 4 + r) * 4 + w] = l[i][r];
    }
}

// ---------- pass 2: 64q x 128s tiles (544 blocks), dbuf LDS K-stage, exp-fold via MFMA C-init ----------
__global__ __launch_bounds__(256, 4) void k_pass2(const _Float16* __restrict__ qh, const _Float16* __restrict__ kh,
                                                  const float* __restrict__ lstat4,
                                                  float* __restrict__ mw, _Float16* __restrict__ mwh) {
    __shared__ float sl[16][64];                   // 4 KB: per-(head,row) log2 bias m
    __shared__ __align__(16) _Float16 kst[2][8192];// 32 KB double-buffered K stage (+store transpose)
    int blk = blockIdx.x;                          // 544 = 2b x 272
    int b = (blk >= 272) ? 1 : 0;
    int i0 = blk - 272 * b;
    int i = (i0 & 7) * 34 + (i0 >> 3);             // XCD-banded (272 = 8 x 34)
    int p = 2 * (int)sqrtf((float)i);
    if (p > 31) p = 31;
    while (fbase(p) > i) p--;
    while (p < 31 && fbase(p + 1) <= i) p++;
    int s128 = i - fbase(p);                       // s128 in [0, ceil((p+1)/2))
    int tid = threadIdx.x, w = tid >> 6, lane = tid & 63, l15 = lane & 15, quad = lane >> 4;
    for (int ii = tid; ii < 1024; ii += 256) {
        int h = ii >> 6, r = ii & 63;
        const float4 pl = *(const float4*)&lstat4[(size_t)((h * 2 + b) * 2048 + p * 64 + r) * 4];
        sl[h][r] = -(__log2f(pl.x + pl.y + pl.z + pl.w) + 4.0f);  // fold 1/sum and 1/16 into exp arg
    }
    int rw = w * 16;
    int rt0 = p * 4 + w;                           // q row-tile (1 per wave)
    int st0 = s128 * 8;                            // k row-tile base (8 per block)
    f32x4 macc[8];
#pragma unroll
    for (int j = 0; j < 8; j++) macc[j] = (f32x4){0.f, 0.f, 0.f, 0.f};

    // prologue: stage K(head 0): 16 chunks of 1KB (skip chunks fully above diagonal)
    {
        const _Float16* kp = kh + (size_t)b * 131072;
#pragma unroll
        for (int inst = 0; inst < 4; inst++) {
            int c = inst * 4 + w;
            if (2 * s128 + ((c >> 1) >> 2) > p) continue;   // never read by compute
            int gc = (st0 + (c >> 1)) * 2 + (c & 1);
            __builtin_amdgcn_global_load_lds((GV*)(kp + (size_t)gc * 512 + lane * 8),
                                             (LV*)(kst[0] + c * 512 + lane * 8), 16, 0, 0);
        }
    }
    __syncthreads();                               // sl + stage0 ready

    for (int n = 0; n < NH_; n++) {
        if (n < NH_ - 1) {                         // prefetch head n+1's K during compute
            const _Float16* kp = kh + (size_t)((n + 1) * 2 + b) * 131072;
#pragma unroll
            for (int inst = 0; inst < 4; inst++) {
                int c = inst * 4 + w;
                if (2 * s128 + ((c >> 1) >> 2) > p) continue;
                int gc = (st0 + (c >> 1)) * 2 + (c & 1);
                __builtin_amdgcn_global_load_lds((GV*)(kp + (size_t)gc * 512 + lane * 8),
                                                 (LV*)(kst[(n + 1) & 1] + c * 512 + lane * 8), 16, 0, 0);
            }
        }
        const _Float16* qb = qh + (size_t)(n * 2 + b) * 131072;
        f16x8 A0 = frag_ld(qb, rt0, 0, 2, l15, quad);
        f16x8 A1 = frag_ld(qb, rt0, 1, 2, l15, quad);
        f32x4 slv = *(const f32x4*)&sl[n][rw + quad * 4];   // per-row log2 bias
        const _Float16* ks = kst[n & 1];
#pragma unroll
        for (int j = 0; j < 8; j++) {
            int s64j = 2 * s128 + (j >> 2);
            if (s64j > p) continue;                // wave-uniform: fully above diagonal
            f16x8 K0 = *(const f16x8*)&ks[(j * 2 + 0) * 512 + quad * 128 + l15 * 8];
            f16x8 K1 = *(const f16x8*)&ks[(j * 2 + 1) * 512 + quad * 128 + l15 * 8];
            f32x4 sc = slv;                        // C-init with bias: MFMA out = score + m
            sc = MFMA(A0, K0, sc);
            sc = MFMA(A1, K1, sc);
            if (s64j == p) {                       // diagonal sub-tile: elementwise mask
                int sg = s128 * 128 + j * 16 + l15;
#pragma unroll
                for (int r = 0; r < 4; r++) {
                    int tg = p * 64 + rw + quad * 4 + r;
                    macc[j][r] += (sg <= tg) ? EXP2(sc[r]) : 0.f;
                }
            } else {
#pragma unroll
                for (int r = 0; r < 4; r++) macc[j][r] += EXP2(sc[r]);
            }
        }
        __syncthreads();                           // next stage ready; current reads done
    }
    // fp32 mw store (skip above-diagonal sub-tiles: prep zero-filled them)
    float* mwb = mw + (size_t)b * T_ * T_;
#pragma unroll
    for (int j = 0; j < 8; j++) {
        if (2 * s128 + (j >> 2) > p) continue;
#pragma unroll
        for (int r = 0; r < 4; r++) {
            int tg = p * 64 + rw + quad * 4 + r;
            int sg = s128 * 128 + j * 16 + l15;
            mwb[(size_t)tg * T_ + sg] = macc[j][r];
        }
    }
    // f16 tiled store via per-wave LDS transpose (4 rounds of 32 cols)
    _Float16* mhb = mwh + (size_t)b * 4194304;
    _Float16* ws16 = kst[0] + w * 1024;            // wave-private 1 KB (post-barrier safe)
    int rowrb = lane & 15, qc = lane >> 4;
#pragma unroll
    for (int cc = 0; cc < 4; cc++) {
        if (2 * s128 + (cc >> 1) > p) continue;    // chunk fully above diagonal: never read
#pragma unroll
        for (int j2 = 0; j2 < 2; j2++)
#pragma unroll
            for (int r = 0; r < 4; r++) {
                int clw = j2 * 16 + l15;
                ws16[(clw >> 3) * 128 + (quad * 4 + r) * 8 + (clw & 7)] = (_Float16)macc[cc * 2 + j2][r];
            }
        f16x8 val = *(const f16x8*)&ws16[qc * 128 + rowrb * 8];
        *(f16x8*)(mhb + (size_t)(rt0 * 64 + (s128 * 4 + cc)) * 512 + qc * 128 + rowrb * 8) = val;
    }
}

// ---------- pass 3 (fused 3a+3b): mean_head (8-wave k-split + LDS reduce) then @Wo + bo ----------
__global__ __launch_bounds__(512) void k_pass3(const _Float16* __restrict__ mwh, const _Float16* __restrict__ vt,
                                               const _Float16* __restrict__ wot, const float* __restrict__ bo,
                                               float* __restrict__ out0) {
    __shared__ float red[8][16][64];               // 32 KB
    __shared__ __align__(16) _Float16 mhs[1024];   // 2 KB: mean_head tile, fragment-chunk layout
    int tid = threadIdx.x, w = tid >> 6, lane = tid & 63, l15 = lane & 15, quad = lane >> 4;
    int blk = blockIdx.x;                          // 256 = 2b x 128 row-tiles (heavy tiles first)
    int b = blk & 1;
    int rtb = 127 - (blk >> 1);
    const _Float16* mb = mwh + (size_t)b * 4194304;
    const _Float16* vb = vt + (size_t)b * 131072;
    int nkc = (rtb * 16 + 47) >> 5;                // causal k-chunk count for this 16-row tile
    f32x4 acc[4];
#pragma unroll
    for (int j = 0; j < 4; j++) acc[j] = (f32x4){0.f, 0.f, 0.f, 0.f};
    for (int kc = w; kc < nkc; kc += 8) {
        f16x8 a = frag_ld(mb, rtb, kc, 64, l15, quad);
#pragma unroll
        for (int j = 0; j < 4; j++) {
            f16x8 bb = frag_ld(vb, j, kc, 64, l15, quad);
            acc[j] = MFMA(a, bb, acc[j]);
        }
    }
#pragma unroll
    for (int j = 0; j < 4; j++)
#pragma unroll
        for (int r = 0; r < 4; r++) red[w][quad * 4 + r][j * 16 + l15] = acc[j][r];
    __syncthreads();
    for (int ii = tid; ii < 1024; ii += 512) {     // reduce 8 wave-partials -> f16 frag tile
        int r = ii >> 6, d = ii & 63;
        float s = red[0][r][d] + red[1][r][d] + red[2][r][d] + red[3][r][d]
                + red[4][r][d] + red[5][r][d] + red[6][r][d] + red[7][r][d];
        mhs[(d >> 5) * 512 + ((d & 31) >> 3) * 128 + r * 8 + (d & 7)] = (_Float16)s;
    }
    __syncthreads();
    // Wo GEMM: wave w -> out cols [w*128, w*128+128)
    f16x8 A0 = frag_ld(mhs, 0, 0, 2, l15, quad);
    f16x8 A1 = frag_ld(mhs, 0, 1, 2, l15, quad);
    f32x4 acc2[8];
#pragma unroll
    for (int j = 0; j < 8; j++) {
        int ct = w * 8 + j;                        // col-tile 0..63
        f16x8 b0 = frag_ld(wot, ct, 0, 2, l15, quad);
        f16x8 b1 = frag_ld(wot, ct, 1, 2, l15, quad);
        f32x4 z = (f32x4){0.f, 0.f, 0.f, 0.f};
        z = MFMA(A0, b0, z);
        z = MFMA(A1, b1, z);
        acc2[j] = z;
    }
    int rowb = (b * 128 + rtb) * 16 + quad * 4;
#pragma unroll
    for (int j = 0; j < 8; j++)
#pragma unroll
        for (int r = 0; r < 4; r++) {
            int col = w * 128 + j * 16 + l15;
            out0[(size_t)(rowb + r) * 1024 + col] = acc2[j][r] + bo[col];
        }
}

extern "C" void kernel_launch(void* const* d_in, const int* in_sizes, int n_in,
                              void* d_out, int out_size, void* d_ws, size_t ws_size,
                              hipStream_t stream) {
    const float* x  = (const float*)d_in[0];
    const float* Wq = (const float*)d_in[1];
    const float* bq = (const float*)d_in[2];
    const float* Wk = (const float*)d_in[3];
    const float* bk = (const float*)d_in[4];
    const float* Wv = (const float*)d_in[5];
    const float* bv = (const float*)d_in[6];
    const float* Wo = (const float*)d_in[7];
    const float* bo = (const float*)d_in[8];
    char* ws = (char*)d_ws;
    _Float16* xb    = (_Float16*)(ws + 0);         // 8 MB (dead after gemm/vproj)
    _Float16* wqk   = (_Float16*)(ws + 8388608);   // 4 MB (dead after gemm)
    _Float16* wvt   = (_Float16*)(ws + 12582912);  // 128 KB (dead after vproj)
    _Float16* mwh   = (_Float16*)(ws + 0);         // 16 MB overlay (written in pass2)
    _Float16* qh    = (_Float16*)(ws + 16777216);  // 8 MB
    _Float16* kh    = (_Float16*)(ws + 25165824);  // 8 MB
    _Float16* vt    = (_Float16*)(ws + 33554432);  // 512 KB
    float*    lstat4= (float*)   (ws + 34078720);  // 1 MB
    _Float16* wot   = (_Float16*)(ws + 39321600);  // 128 KB
    float* out0 = (float*)d_out;
    float* mw   = out0 + (size_t)BT_ * H_;

    k_prep   <<<1384, 256, 0, stream>>>(x, Wq, Wk, Wv, Wo, xb, wqk, wvt, wot, mw);
    k_gemm   <<<768,  256, 0, stream>>>(xb, wqk, bq, bk, wvt, bv, qh, kh, vt);
    k_pass1  <<<512,  256, 0, stream>>>(qh, kh, lstat4);
    k_pass2  <<<544,  256, 0, stream>>>(qh, kh, lstat4, mw, mwh);
    k_pass3  <<<256,  512, 0, stream>>>(mwh, vt, wot, bo, out0);
}

// Round 5
// 189.352 us; speedup vs baseline: 1.0645x; 1.0645x over previous
//
#include <hip/hip_runtime.h>
#include <hip/hip_bf16.h>

#define B_ 2
#define T_ 2048
#define H_ 1024
#define NH_ 16
#define D_ 64
#define BT_ (B_*T_)
#define SCALE_ 0.125f
#define LOG2E_ 1.4426950408889634f

typedef _Float16 f16x8 __attribute__((ext_vector_type(8)));
typedef float f32x4 __attribute__((ext_vector_type(4)));

#define MFMA(a,b,c) __builtin_amdgcn_mfma_f32_16x16x32_f16((a),(b),(c),0,0,0)
#define EXP2(x) __builtin_amdgcn_exp2f(x)

typedef const __attribute__((address_space(1))) void GV;
typedef __attribute__((address_space(3))) void LV;

// Fragment-tiled layout: matrix [R x C] consumed by MFMA with k-dim = C.
// 16-row tiles, 32-wide k-chunks; chunk block = [quad(k/8)][row%16][k%8] = 512 f16 = 1KB.
__device__ __forceinline__ size_t toff(int r, int c, int C) {
    return (size_t)((r >> 4) * (C >> 5) + (c >> 5)) * 512 + (size_t)(((c & 31) >> 3) * 128 + (r & 15) * 8 + (c & 7));
}
__device__ __forceinline__ f16x8 frag_ld(const _Float16* base, int rt, int kc, int Cc, int l15, int quad) {
    return *(const f16x8*)(base + (size_t)(rt * Cc + kc) * 512 + quad * 128 + l15 * 8);
}
// pass2 strip-base: number of 128-wide s-tiles in strips < p. f(2m)=m*m+m, f(2m+1)=(m+1)^2
__device__ __forceinline__ int fbase(int p) {
    int m = p >> 1;
    return (p & 1) ? (m + 1) * (m + 1) : m * m + m;
}

// ---------- prep: all stores are contiguous f16x8 bursts; transposes are load-side ----------
// blocks: [0,256) x-cast | [256,384) wqk | [384,388) wvt | [388,392) wot | [392,1384) mw-zero
__global__ __launch_bounds__(256) void k_prep(const float* __restrict__ x,
                                              const float* __restrict__ Wq, const float* __restrict__ Wk,
                                              const float* __restrict__ Wv, const float* __restrict__ Wo,
                                              _Float16* __restrict__ xb, _Float16* __restrict__ wqk,
                                              _Float16* __restrict__ wvt, _Float16* __restrict__ wot,
                                              float* __restrict__ mw) {
    int blk = blockIdx.x, tid = threadIdx.x;
    if (blk < 256) {                               // cast x: 16 t-rows/block, output tile contiguous 32KB
        const float* xs = x + ((size_t)blk << 14);
        _Float16* dstb = xb + ((size_t)blk << 14);
#pragma unroll
        for (int it = 0; it < 8; it++) {
            int E = it * 2048 + tid * 8;
            int rr = (E >> 3) & 15;
            int h = (E >> 9) * 32 + ((E >> 7) & 3) * 8;
            const float* p = xs + (size_t)rr * 1024 + h;
            float4 f0 = *(const float4*)p;
            float4 f1 = *(const float4*)(p + 4);
            f16x8 o;
            o[0]=(_Float16)f0.x; o[1]=(_Float16)f0.y; o[2]=(_Float16)f0.z; o[3]=(_Float16)f0.w;
            o[4]=(_Float16)f1.x; o[5]=(_Float16)f1.y; o[6]=(_Float16)f1.z; o[7]=(_Float16)f1.w;
            *(f16x8*)(dstb + E) = o;
        }
    } else if (blk < 384) {                        // wqk: one 16-row c-tile per block, stride-64 gathers
        int ct = blk - 256;                        // 0..63 q-tiles, 64..127 k-tiles
        const float* W = (ct < 64) ? Wq : Wk;
        int head = (ct >> 2) & 15;
        int dbase = (ct & 3) * 16;
        _Float16* dstb = wqk + ((size_t)ct << 14);
#pragma unroll
        for (int it = 0; it < 8; it++) {
            int E = it * 2048 + tid * 8;
            int rr = (E >> 3) & 15;
            int h = (E >> 9) * 32 + ((E >> 7) & 3) * 8;
            const float* src = W + (size_t)head * 65536 + (size_t)h * 64 + dbase + rr;
            f16x8 o;
#pragma unroll
            for (int e = 0; e < 8; e++) o[e] = (_Float16)src[(size_t)e * 64];
            *(f16x8*)(dstb + E) = o;
        }
    } else if (blk < 388) {                        // wvt: rows=d (4 tiles), cols=h, stride-64 gathers
        int rt = blk - 384;
        _Float16* dstb = wvt + ((size_t)rt << 14);
#pragma unroll
        for (int it = 0; it < 8; it++) {
            int E = it * 2048 + tid * 8;
            int rr = (E >> 3) & 15;
            int h = (E >> 9) * 32 + ((E >> 7) & 3) * 8;
            const float* src = Wv + (size_t)h * 64 + rt * 16 + rr;
            f16x8 o;
#pragma unroll
            for (int e = 0; e < 8; e++) o[e] = (_Float16)src[(size_t)e * 64];
            *(f16x8*)(dstb + E) = o;
        }
    } else if (blk < 392) {                        // wot: rows=h (C=64), stride-1024 gathers
        int bl = blk - 388;
#pragma unroll
        for (int it = 0; it < 8; it++) {
            int G = bl * 16384 + it * 2048 + tid * 8;
            int rt = G >> 10;
            int rem = G & 1023;
            int rr = (rem >> 3) & 15;
            int dd = (rem >> 9) * 32 + ((rem >> 7) & 3) * 8;
            const float* src = Wo + (size_t)dd * 1024 + rt * 16 + rr;
            f16x8 o;
#pragma unroll
            for (int e = 0; e < 8; e++) o[e] = (_Float16)src[(size_t)e * 1024];
            *(f16x8*)(wot + G) = o;
        }
    } else {                                       // zero upper-tri tiles (992)
        int iz = blk - 392;
        int b = (iz >= 496) ? 1 : 0;
        int i = iz - b * 496;
        int s64 = (int)((sqrtf(8.f * i + 1.f) + 1.f) * 0.5f);
        if (s64 * (s64 - 1) / 2 > i) s64--;
        if ((s64 + 1) * s64 / 2 <= i) s64++;
        int q64 = i - s64 * (s64 - 1) / 2;         // q64 < s64
        float4 z = {0.f, 0.f, 0.f, 0.f};
#pragma unroll
        for (int it = 0; it < 4; it++) {
            int idx = it * 256 + tid;
            int r = idx >> 4, c4 = idx & 15;
            *(float4*)&mw[(size_t)(b * T_ + q64 * 64 + r) * T_ + s64 * 64 + c4 * 4] = z;
        }
    }
}

// ---------- fused: Q||K GEMM (blocks 0..511, BK=64) + V projection (blocks 512..767) ----------
__global__ __launch_bounds__(256) void k_gemm(const _Float16* __restrict__ xb, const _Float16* __restrict__ wqk,
                                              const float* __restrict__ bq, const float* __restrict__ bk,
                                              const _Float16* __restrict__ wvt, const float* __restrict__ bv,
                                              _Float16* __restrict__ qh, _Float16* __restrict__ kh,
                                              _Float16* __restrict__ vt) {
    __shared__ __align__(16) unsigned char smem[32768];
    _Float16* As = (_Float16*)smem;                // 16 KB
    _Float16* Bs = (_Float16*)(smem + 16384);      // 16 KB
    int tid = threadIdx.x, w = tid >> 6, lane = tid & 63, l15 = lane & 15, quad = lane >> 4;
    if (blockIdx.x >= 512) {                       // ---- vproj path ----
        float (*red)[16][64] = (float(*)[16][64])smem;
        int rt = blockIdx.x - 512;
        f32x4 acc[4];
#pragma unroll
        for (int j = 0; j < 4; j++) acc[j] = (f32x4){0.f, 0.f, 0.f, 0.f};
        for (int q = 0; q < 8; q++) {
            int kc = w * 8 + q;
            f16x8 a = frag_ld(xb, rt, kc, 32, l15, quad);
#pragma unroll
            for (int j = 0; j < 4; j++) {
                f16x8 bb = frag_ld(wvt, j, kc, 32, l15, quad);
                acc[j] = MFMA(a, bb, acc[j]);
            }
        }
#pragma unroll
        for (int j = 0; j < 4; j++)
#pragma unroll
            for (int r = 0; r < 4; r++) red[w][quad * 4 + r][j * 16 + l15] = acc[j][r];
        __syncthreads();
        int r = tid >> 4, dg = tid & 15;
        int b = rt >> 7, tt = (rt & 127) * 16 + r;
        _Float16* vtb = vt + (size_t)b * 131072;
#pragma unroll
        for (int e = 0; e < 4; e++) {
            int d = dg * 4 + e;
            float s = red[0][r][d] + red[1][r][d] + red[2][r][d] + red[3][r][d] + bv[d];
            vtb[toff(d, tt, 2048)] = (_Float16)s;
        }
        return;
    }
    // ---- GEMM path, BK=64 ----
    int bm = blockIdx.x >> 4, bn = blockIdx.x & 15;
    int rowbase = (w >> 1) * 64, colbase = (w & 1) * 64;
    f32x4 acc[4][4];
#pragma unroll
    for (int i = 0; i < 4; i++)
#pragma unroll
        for (int j = 0; j < 4; j++) acc[i][j] = (f32x4){0.f, 0.f, 0.f, 0.f};

    for (int kk = 0; kk < 16; kk++) {
        __syncthreads();
#pragma unroll
        for (int p = 0; p < 4; p++) {
            int c = w * 4 + p;                     // 0..15: rowtile c>>1, k-chunk c&1
            __builtin_amdgcn_global_load_lds((GV*)(xb  + ((size_t)((bm * 8 + (c >> 1)) * 32 + kk * 2 + (c & 1))) * 512 + lane * 8),
                                             (LV*)(As + c * 512 + lane * 8), 16, 0, 0);
            __builtin_amdgcn_global_load_lds((GV*)(wqk + ((size_t)((bn * 8 + (c >> 1)) * 32 + kk * 2 + (c & 1))) * 512 + lane * 8),
                                             (LV*)(Bs + c * 512 + lane * 8), 16, 0, 0);
        }
        __syncthreads();
#pragma unroll
        for (int kc = 0; kc < 2; kc++) {
            f16x8 a[4], bf[4];
#pragma unroll
            for (int i = 0; i < 4; i++) a[i]  = *(const f16x8*)&As[((rowbase >> 4) + i) * 1024 + kc * 512 + quad * 128 + l15 * 8];
#pragma unroll
            for (int j = 0; j < 4; j++) bf[j] = *(const f16x8*)&Bs[((colbase >> 4) + j) * 1024 + kc * 512 + quad * 128 + l15 * 8];
#pragma unroll
            for (int i = 0; i < 4; i++)
#pragma unroll
                for (int j = 0; j < 4; j++) acc[i][j] = MFMA(a[i], bf[j], acc[i][j]);
        }
    }
    __syncthreads();                               // reuse As/Bs for epilogue staging
    int b = (bm * 128) >> 11;
    int t_base = (bm * 128) & 2047;
    int rtbase = (t_base + rowbase) >> 4;
    bool isq = (bn < 8);
    int c2base = isq ? (bn * 128 + colbase) : (bn * 128 + colbase - 1024);
    int n = c2base >> 6;
    _Float16* dst = (isq ? qh : kh) + (size_t)(n * 2 + b) * 131072;
    const float* bias_p = isq ? bq : bk;
    float qs = SCALE_ * LOG2E_;                    // fold softmax scale + log2e into q
    int i2 = lane >> 4, rowrb = lane & 15;
#pragma unroll
    for (int j = 0; j < 4; j++) {
        float bias = bias_p[c2base + j * 16 + l15];
        _Float16* stg = ((j & 1) ? Bs : As) + w * 1024;
#pragma unroll
        for (int i = 0; i < 4; i++)
#pragma unroll
            for (int r = 0; r < 4; r++) {
                float v = acc[i][j][r] + bias;
                if (isq) v *= qs;
                stg[(i * 16 + quad * 4 + r) * 16 + l15] = (_Float16)v;
            }
#pragma unroll
        for (int oct = 0; oct < 2; oct++) {
            f16x8 val = *(const f16x8*)&stg[(i2 * 16 + rowrb) * 16 + oct * 8];
            int dd0 = j * 16 + oct * 8;
            *(f16x8*)(dst + (size_t)((rtbase + i2) * 2 + (dd0 >> 5)) * 512 + ((dd0 & 31) >> 3) * 128 + rowrb * 8) = val;
        }
    }
}

// ---------- pass 1: causal row sum-exp2; 64-row strips, heavy-first, XCD-local (n,b) ----------
__global__ __launch_bounds__(256) void k_pass1(const _Float16* __restrict__ qh, const _Float16* __restrict__ kh,
                                               float* __restrict__ lstat4) {
    int tid = threadIdx.x, w = tid >> 6, lane = tid & 63, l15 = lane & 15, quad = lane >> 4;
    int blk = blockIdx.x;                          // 1024 blocks: s4(5) | nb(5)
    int nb = blk & 31;                             // blk&7 ~ XCD -> each XCD serves 4 (n,b) pairs
    int s4 = 31 - (blk >> 5);                      // heavy strips dispatch first
    int n = nb >> 1, b = nb & 1;
    const _Float16* qb = qh + (size_t)(n * 2 + b) * 131072;
    const _Float16* kp = kh + (size_t)(n * 2 + b) * 131072;
    int rt0 = s4 * 4;
    f16x8 aq[4][2];
#pragma unroll
    for (int i = 0; i < 4; i++)
#pragma unroll
        for (int kk = 0; kk < 2; kk++) aq[i][kk] = frag_ld(qb, rt0 + i, kk, 2, l15, quad);
    float l[4][4];
#pragma unroll
    for (int i = 0; i < 4; i++)
#pragma unroll
        for (int r = 0; r < 4; r++) l[i][r] = 0.f;
    int total = 4 * s4 + 4;
    int st_lo = (w * total) >> 2;
    int st_hi = ((w + 1) * total) >> 2;
    for (int st = st_lo; st < st_hi; st++) {
        f16x8 c0 = frag_ld(kp, st, 0, 2, l15, quad);
        f16x8 c1 = frag_ld(kp, st, 1, 2, l15, quad);
#pragma unroll
        for (int i = 0; i < 4; i++) {
            if (st > rt0 + i) continue;            // wave-uniform branch
            f32x4 sc = (f32x4){0.f, 0.f, 0.f, 0.f};
            sc = MFMA(aq[i][0], c0, sc);
            sc = MFMA(aq[i][1], c1, sc);
            if (st == rt0 + i) {
#pragma unroll
                for (int r = 0; r < 4; r++)
                    if (l15 <= quad * 4 + r) l[i][r] += EXP2(sc[r]);
            } else {
#pragma unroll
                for (int r = 0; r < 4; r++) l[i][r] += EXP2(sc[r]);
            }
        }
    }
#pragma unroll
    for (int off = 1; off < 16; off <<= 1)
#pragma unroll
        for (int i = 0; i < 4; i++)
#pragma unroll
            for (int r = 0; r < 4; r++) l[i][r] += __shfl_xor(l[i][r], off, 64);
    if (l15 == 0) {
        int base = (n * 2 + b) * 2048 + s4 * 64;
#pragma unroll
        for (int i = 0; i < 4; i++)
#pragma unroll
            for (int r = 0; r < 4; r++)
                lstat4[(size_t)(base + i * 16 + quad * 4 + r) * 4 + w] = l[i][r];
    }
}

// ---------- pass 2: 64q x 128s tiles (544 blocks), dbuf LDS K-stage, exp-fold via MFMA C-init ----------
__global__ __launch_bounds__(256, 4) void k_pass2(const _Float16* __restrict__ qh, const _Float16* __restrict__ kh,
                                                  const float* __restrict__ lstat4,
                                                  float* __restrict__ mw, _Float16* __restrict__ mwh) {
    __shared__ float sl[16][64];                   // 4 KB: per-(head,row) log2 bias m
    __shared__ __align__(16) _Float16 kst[2][8192];// 32 KB double-buffered K stage (+store transpose)
    int blk = blockIdx.x;                          // 544 = 2b x 272
    int b = (blk >= 272) ? 1 : 0;
    int i0 = blk - 272 * b;
    int i = (i0 & 7) * 34 + (i0 >> 3);             // XCD-banded (272 = 8 x 34)
    int p = 2 * (int)sqrtf((float)i);
    if (p > 31) p = 31;
    while (fbase(p) > i) p--;
    while (p < 31 && fbase(p + 1) <= i) p++;
    int s128 = i - fbase(p);                       // s128 in [0, ceil((p+1)/2))
    int tid = threadIdx.x, w = tid >> 6, lane = tid & 63, l15 = lane & 15, quad = lane >> 4;
    for (int ii = tid; ii < 1024; ii += 256) {
        int h = ii >> 6, r = ii & 63;
        const float4 pl = *(const float4*)&lstat4[(size_t)((h * 2 + b) * 2048 + p * 64 + r) * 4];
        sl[h][r] = -(__log2f(pl.x + pl.y + pl.z + pl.w) + 4.0f);  // fold 1/sum and 1/16 into exp arg
    }
    int rw = w * 16;
    int rt0 = p * 4 + w;                           // q row-tile (1 per wave)
    int st0 = s128 * 8;                            // k row-tile base (8 per block)
    f32x4 macc[8];
#pragma unroll
    for (int j = 0; j < 8; j++) macc[j] = (f32x4){0.f, 0.f, 0.f, 0.f};

    // prologue: stage K(head 0): 16 chunks of 1KB (skip chunks fully above diagonal)
    {
        const _Float16* kp = kh + (size_t)b * 131072;
#pragma unroll
        for (int inst = 0; inst < 4; inst++) {
            int c = inst * 4 + w;
            if (2 * s128 + ((c >> 1) >> 2) > p) continue;   // never read by compute
            int gc = (st0 + (c >> 1)) * 2 + (c & 1);
            __builtin_amdgcn_global_load_lds((GV*)(kp + (size_t)gc * 512 + lane * 8),
                                             (LV*)(kst[0] + c * 512 + lane * 8), 16, 0, 0);
        }
    }
    __syncthreads();                               // sl + stage0 ready

    for (int n = 0; n < NH_; n++) {
        if (n < NH_ - 1) {                         // prefetch head n+1's K during compute
            const _Float16* kp = kh + (size_t)((n + 1) * 2 + b) * 131072;
#pragma unroll
            for (int inst = 0; inst < 4; inst++) {
                int c = inst * 4 + w;
                if (2 * s128 + ((c >> 1) >> 2) > p) continue;
                int gc = (st0 + (c >> 1)) * 2 + (c & 1);
                __builtin_amdgcn_global_load_lds((GV*)(kp + (size_t)gc * 512 + lane * 8),
                                                 (LV*)(kst[(n + 1) & 1] + c * 512 + lane * 8), 16, 0, 0);
            }
        }
        const _Float16* qb = qh + (size_t)(n * 2 + b) * 131072;
        f16x8 A0 = frag_ld(qb, rt0, 0, 2, l15, quad);
        f16x8 A1 = frag_ld(qb, rt0, 1, 2, l15, quad);
        f32x4 slv = *(const f32x4*)&sl[n][rw + quad * 4];   // per-row log2 bias
        const _Float16* ks = kst[n & 1];
#pragma unroll
        for (int j = 0; j < 8; j++) {
            int s64j = 2 * s128 + (j >> 2);
            if (s64j > p) continue;                // wave-uniform: fully above diagonal
            f16x8 K0 = *(const f16x8*)&ks[(j * 2 + 0) * 512 + quad * 128 + l15 * 8];
            f16x8 K1 = *(const f16x8*)&ks[(j * 2 + 1) * 512 + quad * 128 + l15 * 8];
            f32x4 sc = slv;                        // C-init with bias: MFMA out = score + m
            sc = MFMA(A0, K0, sc);
            sc = MFMA(A1, K1, sc);
            if (s64j == p) {                       // diagonal sub-tile: elementwise mask
                int sg = s128 * 128 + j * 16 + l15;
#pragma unroll
                for (int r = 0; r < 4; r++) {
                    int tg = p * 64 + rw + quad * 4 + r;
                    macc[j][r] += (sg <= tg) ? EXP2(sc[r]) : 0.f;
                }
            } else {
#pragma unroll
                for (int r = 0; r < 4; r++) macc[j][r] += EXP2(sc[r]);
            }
        }
        __syncthreads();                           // next stage ready; current reads done
    }
    // fp32 mw store (skip above-diagonal sub-tiles: prep zero-filled them)
    float* mwb = mw + (size_t)b * T_ * T_;
#pragma unroll
    for (int j = 0; j < 8; j++) {
        if (2 * s128 + (j >> 2) > p) continue;
#pragma unroll
        for (int r = 0; r < 4; r++) {
            int tg = p * 64 + rw + quad * 4 + r;
            int sg = s128 * 128 + j * 16 + l15;
            mwb[(size_t)tg * T_ + sg] = macc[j][r];
        }
    }
    // f16 tiled store via per-wave LDS transpose (4 rounds of 32 cols)
    _Float16* mhb = mwh + (size_t)b * 4194304;
    _Float16* ws16 = kst[0] + w * 1024;            // wave-private 1 KB (post-barrier safe)
    int rowrb = lane & 15, qc = lane >> 4;
#pragma unroll
    for (int cc = 0; cc < 4; cc++) {
        if (2 * s128 + (cc >> 1) > p) continue;    // chunk fully above diagonal: never read
#pragma unroll
        for (int j2 = 0; j2 < 2; j2++)
#pragma unroll
            for (int r = 0; r < 4; r++) {
                int clw = j2 * 16 + l15;
                ws16[(clw >> 3) * 128 + (quad * 4 + r) * 8 + (clw & 7)] = (_Float16)macc[cc * 2 + j2][r];
            }
        f16x8 val = *(const f16x8*)&ws16[qc * 128 + rowrb * 8];
        *(f16x8*)(mhb + (size_t)(rt0 * 64 + (s128 * 4 + cc)) * 512 + qc * 128 + rowrb * 8) = val;
    }
}

// ---------- pass 3 (fused 3a+3b): mean_head (8-wave k-split + LDS reduce) then @Wo + bo ----------
__global__ __launch_bounds__(512) void k_pass3(const _Float16* __restrict__ mwh, const _Float16* __restrict__ vt,
                                               const _Float16* __restrict__ wot, const float* __restrict__ bo,
                                               float* __restrict__ out0) {
    __shared__ float red[8][16][64];               // 32 KB
    __shared__ __align__(16) _Float16 mhs[1024];   // 2 KB: mean_head tile, fragment-chunk layout
    int tid = threadIdx.x, w = tid >> 6, lane = tid & 63, l15 = lane & 15, quad = lane >> 4;
    int blk = blockIdx.x;                          // 256 = 2b x 128 row-tiles (heavy tiles first)
    int b = blk & 1;
    int rtb = 127 - (blk >> 1);
    const _Float16* mb = mwh + (size_t)b * 4194304;
    const _Float16* vb = vt + (size_t)b * 131072;
    int nkc = (rtb * 16 + 47) >> 5;                // causal k-chunk count for this 16-row tile
    f32x4 acc[4];
#pragma unroll
    for (int j = 0; j < 4; j++) acc[j] = (f32x4){0.f, 0.f, 0.f, 0.f};
    for (int kc = w; kc < nkc; kc += 8) {
        f16x8 a = frag_ld(mb, rtb, kc, 64, l15, quad);
#pragma unroll
        for (int j = 0; j < 4; j++) {
            f16x8 bb = frag_ld(vb, j, kc, 64, l15, quad);
            acc[j] = MFMA(a, bb, acc[j]);
        }
    }
#pragma unroll
    for (int j = 0; j < 4; j++)
#pragma unroll
        for (int r = 0; r < 4; r++) red[w][quad * 4 + r][j * 16 + l15] = acc[j][r];
    __syncthreads();
    for (int ii = tid; ii < 1024; ii += 512) {     // reduce 8 wave-partials -> f16 frag tile
        int r = ii >> 6, d = ii & 63;
        float s = red[0][r][d] + red[1][r][d] + red[2][r][d] + red[3][r][d]
                + red[4][r][d] + red[5][r][d] + red[6][r][d] + red[7][r][d];
        mhs[(d >> 5) * 512 + ((d & 31) >> 3) * 128 + r * 8 + (d & 7)] = (_Float16)s;
    }
    __syncthreads();
    // Wo GEMM: wave w -> out cols [w*128, w*128+128)
    f16x8 A0 = frag_ld(mhs, 0, 0, 2, l15, quad);
    f16x8 A1 = frag_ld(mhs, 0, 1, 2, l15, quad);
    f32x4 acc2[8];
#pragma unroll
    for (int j = 0; j < 8; j++) {
        int ct = w * 8 + j;                        // col-tile 0..63
        f16x8 b0 = frag_ld(wot, ct, 0, 2, l15, quad);
        f16x8 b1 = frag_ld(wot, ct, 1, 2, l15, quad);
        f32x4 z = (f32x4){0.f, 0.f, 0.f, 0.f};
        z = MFMA(A0, b0, z);
        z = MFMA(A1, b1, z);
        acc2[j] = z;
    }
    int rowb = (b * 128 + rtb) * 16 + quad * 4;
#pragma unroll
    for (int j = 0; j < 8; j++)
#pragma unroll
        for (int r = 0; r < 4; r++) {
            int col = w * 128 + j * 16 + l15;
            out0[(size_t)(rowb + r) * 1024 + col] = acc2[j][r] + bo[col];
        }
}

extern "C" void kernel_launch(void* const* d_in, const int* in_sizes, int n_in,
                              void* d_out, int out_size, void* d_ws, size_t ws_size,
                              hipStream_t stream) {
    const float* x  = (const float*)d_in[0];
    const float* Wq = (const float*)d_in[1];
    const float* bq = (const float*)d_in[2];
    const float* Wk = (const float*)d_in[3];
    const float* bk = (const float*)d_in[4];
    const float* Wv = (const float*)d_in[5];
    const float* bv = (const float*)d_in[6];
    const float* Wo = (const float*)d_in[7];
    const float* bo = (const float*)d_in[8];
    char* ws = (char*)d_ws;
    _Float16* xb    = (_Float16*)(ws + 0);         // 8 MB (dead after gemm/vproj)
    _Float16* wqk   = (_Float16*)(ws + 8388608);   // 4 MB (dead after gemm)
    _Float16* wvt   = (_Float16*)(ws + 12582912);  // 128 KB (dead after vproj)
    _Float16* mwh   = (_Float16*)(ws + 0);         // 16 MB overlay (written in pass2)
    _Float16* qh    = (_Float16*)(ws + 16777216);  // 8 MB
    _Float16* kh    = (_Float16*)(ws + 25165824);  // 8 MB
    _Float16* vt    = (_Float16*)(ws + 33554432);  // 512 KB
    float*    lstat4= (float*)   (ws + 34078720);  // 1 MB
    _Float16* wot   = (_Float16*)(ws + 39321600);  // 128 KB
    float* out0 = (float*)d_out;
    float* mw   = out0 + (size_t)BT_ * H_;

    k_prep   <<<1384, 256, 0, stream>>>(x, Wq, Wk, Wv, Wo, xb, wqk, wvt, wot, mw);
    k_gemm   <<<768,  256, 0, stream>>>(xb, wqk, bq, bk, wvt, bv, qh, kh, vt);
    k_pass1  <<<1024, 256, 0, stream>>>(qh, kh, lstat4);
    k_pass2  <<<544,  256, 0, stream>>>(qh, kh, lstat4, mw, mwh);
    k_pass3  <<<256,  512, 0, stream>>>(mwh, vt, wot, bo, out0);
}